// Round 1
// 1916.035 us; speedup vs baseline: 1.0304x; 1.0304x over previous
//
#include <hip/hip_runtime.h>
#include <hip/hip_bf16.h>

#define TSEQ  200
#define BATCH 256
#define INDIM 32
#define HID   512
#define GATES 2048

typedef __bf16 bf16x8 __attribute__((ext_vector_type(8)));
typedef float  f32x4  __attribute__((ext_vector_type(4)));
typedef unsigned long long u64;

// ---- workspace layout (bytes) ----
static constexpr size_t OFF_PW_IH0 = 0;          // 2048*32*2  = 128 KB
static constexpr size_t OFF_PW_HH0 = 0x20000;    // 2048*512*2 = 2 MB
static constexpr size_t OFF_PW_IH1 = 0x220000;   // 2 MB
static constexpr size_t OFF_PW_HH1 = 0x420000;   // 2 MB
static constexpr size_t OFF_B0     = 0x620000;   // 8 KB
static constexpr size_t OFF_B1     = 0x622000;   // 8 KB
static constexpr size_t OFF_H1     = 0x624000;   // h1 ring: 4 slots x 256 KB (layer0 may run 2 ahead)
static constexpr size_t OFF_H2     = 0x724000;   // h2 ping-pong: 2 slots x 256 KB
static constexpr size_t OFF_CTR    = 0x7A4000;   // per-group flag lines (32 dwords, 256B apart)
static constexpr size_t OFF_H2P    = 0x7A6000;   // 512 KB fp32 (final h2)
static constexpr size_t ZERO_OFF   = OFF_H1;
static constexpr size_t ZERO_LEN   = OFF_H2P + 0x80000 - OFF_H1;

__device__ __forceinline__ float sigm(float v) { return 1.f / (1.f + __expf(-v)); }

__device__ __forceinline__ bf16x8 as_bf16x8(f32x4 v) {
    union { f32x4 f; bf16x8 b; } u; u.f = v; return u.b;
}

// Coherent (L2-bypassing, sc1) 16-byte fragment load as 2x relaxed agent atomics.
__device__ __forceinline__ bf16x8 load_frag_coh(const bf16x8* p) {
    const u64* q = (const u64*)p;
    union { u64 u[2]; bf16x8 v; } cv;
    cv.u[0] = __hip_atomic_load(q,     __ATOMIC_RELAXED, __HIP_MEMORY_SCOPE_AGENT);
    cv.u[1] = __hip_atomic_load(q + 1, __ATOMIC_RELAXED, __HIP_MEMORY_SCOPE_AGENT);
    return cv.v;
}

// Pack weight matrix W[2048][K] (fp32, row-major) into MFMA B-fragment order (bf16).
__global__ void pack_w(const float* __restrict__ W, __bf16* __restrict__ out, int ktlog2)
{
    int tid = blockIdx.x * 256 + threadIdx.x;
    int K = 32 << ktlog2;
    int j    = tid & 7;
    int lane = (tid >> 3) & 63;
    int rest = tid >> 9;
    int kt   = rest & ((1 << ktlog2) - 1);
    int r2   = rest >> ktlog2;
    int lnt  = r2 & 7;
    int bn   = r2 >> 3;
    int type = lnt >> 1, half = lnt & 1;
    int g    = type * 512 + bn * 32 + half * 16 + (lane & 15);
    int kcol = kt * 32 + (lane >> 4) * 8 + j;
    out[tid] = (__bf16)W[g * K + kcol];
}

__global__ void bias_comb(const float* __restrict__ a0, const float* __restrict__ a1,
                          const float* __restrict__ a2, const float* __restrict__ a3,
                          float* __restrict__ o0, float* __restrict__ o1)
{
    int tid = blockIdx.x * 256 + threadIdx.x;
    if (tid < GATES) { o0[tid] = a0[tid] + a1[tid]; o1[tid] = a2[tid] + a3[tid]; }
}

// Persistent pipelined 2-layer LSTM, weights register-resident.
// Grid: 256 blocks x 256 threads (4 waves). Blocks 0..127 layer0, 128..255 layer1.
// Sync redesign vs previous version:
//   - per-block FLAG STORES (plain sc1 stores to distinct dwords of one line per
//     group) replace the single fetch_add counter -> no MALL atomic-ALU
//     serialization, no RMW queueing behind the poll flood.
//   - poll = ONE coalesced 32-lane load of the whole flag line, per-lane
//     threshold compare, divergent retry.
//   - h1 ring deepened to 4 slots: layer0 may run up to 2 steps ahead of
//     layer1 (it only needs layer1 flags >= k-1 for overwrite protection),
//     so steady-state sync is a 16-participant barrier per layer, and the
//     cross-layer checks are normally pre-satisfied.
__global__ __launch_bounds__(256, 1) void lstm_persist(const float* __restrict__ x,
                                                       const float* __restrict__ wfc,
                                                       const float* __restrict__ bfc,
                                                       char* __restrict__ ws,
                                                       float* __restrict__ out)
{
    const int layer = blockIdx.x >> 7;
    const int lb    = blockIdx.x & 127;
    const int mtp   = lb >> 4;            // batch group: [mtp*32, +32)
    const int bn    = lb & 15;            // hidden tile: [bn*32, +32)
    const int wid   = threadIdx.x >> 6;
    const int half  = wid & 1;
    const int kh    = wid >> 1;
    const int lane  = threadIdx.x & 63;
    const int q     = lane >> 4;
    const int c16   = lane & 15;
    unsigned* flg   = (unsigned*)(ws + OFF_CTR) + (size_t)mtp * 64;  // 32 flags, 1 line

    __shared__ float  red[2][64][33];     // padded: conflict-free cross-wave reduction
    __shared__ __bf16 htr[1024];          // h transpose staging (kh0 waves only)

    const float* bias = (const float*)(ws + (layer ? OFF_B1 : OFF_B0));
    const int hidx = bn * 32 + half * 16 + c16;     // C/D col = lane&15
    const float bi  = bias[hidx];
    const float bff = bias[512 + hidx];
    const float bg  = bias[1024 + hidx];
    const float bo  = bias[1536 + hidx];

    const bf16x8* __restrict__ pBx = (const bf16x8*)(ws + OFF_PW_IH0);
    const bf16x8* __restrict__ pBh = (const bf16x8*)(ws + OFF_PW_HH0);
    const bf16x8* __restrict__ pB1 = (const bf16x8*)(ws + OFF_PW_IH1);
    const bf16x8* __restrict__ pB2 = (const bf16x8*)(ws + OFF_PW_HH1);
    float* __restrict__ h2p = (float*)(ws + OFF_H2P);

    // ---- preload weight slice into registers (once; written by prior dispatch) ----
    f32x4 Bw[64];                         // layer1: [kt(16)][ty(4)]; layer0: [kt(8)][ty(4)]
    f32x4 Bx[4];                          // layer0 x-projection frags
    if (layer == 0) {
        #pragma unroll
        for (int j = 0; j < 8; ++j)
            #pragma unroll
            for (int ty = 0; ty < 4; ++ty)
                Bw[j * 4 + ty] = *(const f32x4*)&pBh[((bn * 8 + ty * 2 + half) * 16 + kh * 8 + j) * 64 + lane];
        #pragma unroll
        for (int ty = 0; ty < 4; ++ty)
            Bx[ty] = *(const f32x4*)&pBx[(bn * 8 + ty * 2 + half) * 64 + lane];
    } else {
        const bf16x8* __restrict__ pW = kh ? pB2 : pB1;
        #pragma unroll
        for (int j = 0; j < 16; ++j)
            #pragma unroll
            for (int ty = 0; ty < 4; ++ty)
                Bw[j * 4 + ty] = *(const f32x4*)&pW[((bn * 8 + ty * 2 + half) * 16 + j) * 64 + lane];
    }

    float creg[8] = {0.f,0.f,0.f,0.f,0.f,0.f,0.f,0.f};   // c state (kh0 waves)

    // 16 A-frag loads (2 m-tiles x 8 kt); relaxed atomics, compiler-clustered
    auto loadA = [&](bf16x8* dst, const bf16x8* pA, int kt0) {
        #pragma unroll
        for (int j = 0; j < 8; ++j) {
            dst[j]     = load_frag_coh(&pA[((mtp * 2 + 0) * 16 + kt0 + j) * 64 + lane]);
            dst[8 + j] = load_frag_coh(&pA[((mtp * 2 + 1) * 16 + kt0 + j) * 64 + lane]);
        }
    };

    for (int k = 0; k <= TSEQ; ++k) {
        const bool active = layer ? (k >= 1) : (k < TSEQ);
        if (active) {
            const int t = k - layer;
            f32x4 acc[2][4] = {};

            // h1 ring: layer0 writes slot k&3 (t=k); both layers read t=k-1 at slot (k+3)&3
            const size_t h1rd = OFF_H1 + (size_t)((k + 3) & 3) * 0x40000;

            if (layer == 0) {
                const bf16x8* __restrict__ pA = (const bf16x8*)(ws + h1rd);
                bf16x8 af[16];
                loadA(af, pA, kh * 8);
                if (kh == 0) {
                    // x projection (K=32); weights already in registers
                    #pragma unroll
                    for (int m = 0; m < 2; ++m) {
                        const int b = (mtp * 2 + m) * 16 + c16;
                        const float* xp = x + ((size_t)b * TSEQ + t) * INDIM + q * 8;
                        float4 xlo = *(const float4*)xp;
                        float4 xhi = *(const float4*)(xp + 4);
                        bf16x8 ax;
                        ax[0] = (__bf16)xlo.x; ax[1] = (__bf16)xlo.y;
                        ax[2] = (__bf16)xlo.z; ax[3] = (__bf16)xlo.w;
                        ax[4] = (__bf16)xhi.x; ax[5] = (__bf16)xhi.y;
                        ax[6] = (__bf16)xhi.z; ax[7] = (__bf16)xhi.w;
                        #pragma unroll
                        for (int ty = 0; ty < 4; ++ty)
                            acc[m][ty] = __builtin_amdgcn_mfma_f32_16x16x32_bf16(ax, as_bf16x8(Bx[ty]), acc[m][ty], 0, 0, 0);
                    }
                }
                #pragma unroll
                for (int j = 0; j < 8; ++j) {
                    #pragma unroll
                    for (int ty = 0; ty < 4; ++ty) {
                        acc[0][ty] = __builtin_amdgcn_mfma_f32_16x16x32_bf16(af[j],     as_bf16x8(Bw[j * 4 + ty]), acc[0][ty], 0, 0, 0);
                        acc[1][ty] = __builtin_amdgcn_mfma_f32_16x16x32_bf16(af[8 + j], as_bf16x8(Bw[j * 4 + ty]), acc[1][ty], 0, 0, 0);
                    }
                }
            } else {
                const bf16x8* __restrict__ pA = kh
                    ? (const bf16x8*)(ws + OFF_H2 + (size_t)((k + 1) & 1) * 0x40000)
                    : (const bf16x8*)(ws + h1rd);
                bf16x8 a0[16], a1[16];
                loadA(a0, pA, 0);
                loadA(a1, pA, 8);
                #pragma unroll
                for (int j = 0; j < 8; ++j) {
                    #pragma unroll
                    for (int ty = 0; ty < 4; ++ty) {
                        acc[0][ty] = __builtin_amdgcn_mfma_f32_16x16x32_bf16(a0[j],     as_bf16x8(Bw[j * 4 + ty]), acc[0][ty], 0, 0, 0);
                        acc[1][ty] = __builtin_amdgcn_mfma_f32_16x16x32_bf16(a0[8 + j], as_bf16x8(Bw[j * 4 + ty]), acc[1][ty], 0, 0, 0);
                    }
                }
                #pragma unroll
                for (int j = 0; j < 8; ++j) {
                    #pragma unroll
                    for (int ty = 0; ty < 4; ++ty) {
                        acc[0][ty] = __builtin_amdgcn_mfma_f32_16x16x32_bf16(a1[j],     as_bf16x8(Bw[(8 + j) * 4 + ty]), acc[0][ty], 0, 0, 0);
                        acc[1][ty] = __builtin_amdgcn_mfma_f32_16x16x32_bf16(a1[8 + j], as_bf16x8(Bw[(8 + j) * 4 + ty]), acc[1][ty], 0, 0, 0);
                    }
                }
            }

            // ---- cross-wave K reduction ----
            if (kh == 1) {
                #pragma unroll
                for (int m = 0; m < 2; ++m)
                    #pragma unroll
                    for (int ty = 0; ty < 4; ++ty)
                        #pragma unroll
                        for (int r = 0; r < 4; ++r)
                            red[half][lane][m * 16 + ty * 4 + r] = acc[m][ty][r];
            }
            __syncthreads();

            if (kh == 0) {
                __bf16* __restrict__ hout = (__bf16*)(ws + (layer
                    ? OFF_H2 + (size_t)(k & 1) * 0x40000
                    : OFF_H1 + (size_t)(k & 3) * 0x40000));
                #pragma unroll
                for (int m = 0; m < 2; ++m) {
                    #pragma unroll
                    for (int r = 0; r < 4; ++r) {
                        float pi = acc[m][0][r] + red[half][lane][m * 16 + r]      + bi;
                        float pf = acc[m][1][r] + red[half][lane][m * 16 + 4 + r]  + bff;
                        float pg = acc[m][2][r] + red[half][lane][m * 16 + 8 + r]  + bg;
                        float po = acc[m][3][r] + red[half][lane][m * 16 + 12 + r] + bo;
                        float cn = sigm(pf) * creg[m * 4 + r] + sigm(pi) * tanhf(pg);
                        float hn = sigm(po) * tanhf(cn);
                        creg[m * 4 + r] = cn;
                        htr[half * 512 + (m * 16 + q * 4 + r) * 16 + c16] = (__bf16)hn;
                        if (layer == 1 && k == TSEQ) {
                            const int b = (mtp * 2 + m) * 16 + q * 4 + r;
                            __hip_atomic_store(&h2p[b * HID + hidx], hn,
                                               __ATOMIC_RELAXED, __HIP_MEMORY_SCOPE_AGENT);
                        }
                    }
                }
                // wave-local LDS transpose -> coalesced 8B coherent h stores
                const int bt   = lane >> 5;
                const int qa1  = (lane >> 4) & 1;
                const int b15r = lane & 15;
                const u64* lp = (const u64*)&htr[half * 512 + (bt * 16 + b15r) * 16 + qa1 * 8];
                u64 v0 = lp[0], v1 = lp[1];
                const int f = (((mtp * 2 + bt) * 16) + bn) * 64 + (half * 2 + qa1) * 16 + b15r;
                u64* gp = (u64*)hout + (size_t)f * 2;
                __hip_atomic_store(gp,     v0, __ATOMIC_RELAXED, __HIP_MEMORY_SCOPE_AGENT);
                __hip_atomic_store(gp + 1, v1, __ATOMIC_RELAXED, __HIP_MEMORY_SCOPE_AGENT);
            }
        }

        // ---- flag barrier: plain per-block stores + one coalesced 32-lane poll ----
        // layer0 lanes: peers (0..15) need k+1; layer1 lanes (16..31) only need
        // k-1 (4-slot h1 overwrite protection) except at the final round, where
        // the FC epilogue needs all of h2p -> full 32-way wait.
        asm volatile("s_waitcnt vmcnt(0)" ::: "memory");
        __syncthreads();
        if (threadIdx.x == 0)
            __hip_atomic_store(flg + layer * 16 + bn, (unsigned)(k + 1),
                               __ATOMIC_RELAXED, __HIP_MEMORY_SCOPE_AGENT);
        if (threadIdx.x < 32) {
            const int need = (layer == 0 && threadIdx.x >= 16 && k < TSEQ) ? (k - 1) : (k + 1);
            while ((int)__hip_atomic_load(flg + threadIdx.x, __ATOMIC_RELAXED,
                                          __HIP_MEMORY_SCOPE_AGENT) < need)
                __builtin_amdgcn_s_sleep(1);
        }
        __syncthreads();
    }

    // ---- fused FC epilogue: one batch per block (group-local mapping) ----
    if (threadIdx.x < 64) {
        const int b = mtp * 32 + layer * 16 + bn;
        const float* h = h2p + b * HID;
        float hv[8];
        #pragma unroll
        for (int j = 0; j < 8; ++j)
            hv[j] = __hip_atomic_load(&h[lane * 8 + j], __ATOMIC_RELAXED, __HIP_MEMORY_SCOPE_AGENT);
        float y[7];
        #pragma unroll
        for (int o = 0; o < 7; ++o) {
            const float* wrow = wfc + o * HID;
            float s = 0.f;
            #pragma unroll
            for (int j = 0; j < 8; ++j) s += hv[j] * wrow[lane * 8 + j];
            #pragma unroll
            for (int off = 32; off >= 1; off >>= 1) s += __shfl_down(s, off);
            y[o] = s;
        }
        if (lane == 0) {
            out[b * 3 + 0] = sigm(y[0] + bfc[0]);
            out[b * 3 + 1] = sigm(y[1] + bfc[1]);
            out[b * 3 + 2] = sigm(y[2] + bfc[2]);
            float r0 = tanhf(y[3] + bfc[3]);
            float r1 = tanhf(y[4] + bfc[4]);
            float r2 = tanhf(y[5] + bfc[5]);
            float r3 = tanhf(y[6] + bfc[6]);
            float n = sqrtf(r0 * r0 + r1 * r1 + r2 * r2 + r3 * r3);
            n = fmaxf(n, 1e-12f);
            out[768 + b * 4 + 0] = r0 / n;
            out[768 + b * 4 + 1] = r1 / n;
            out[768 + b * 4 + 2] = r2 / n;
            out[768 + b * 4 + 3] = r3 / n;
        }
    }
}

extern "C" void kernel_launch(void* const* d_in, const int* in_sizes, int n_in,
                              void* d_out, int out_size, void* d_ws, size_t ws_size,
                              hipStream_t stream)
{
    const float* x    = (const float*)d_in[0];
    const float* wih0 = (const float*)d_in[1];
    const float* whh0 = (const float*)d_in[2];
    const float* bih0 = (const float*)d_in[3];
    const float* bhh0 = (const float*)d_in[4];
    const float* wih1 = (const float*)d_in[5];
    const float* whh1 = (const float*)d_in[6];
    const float* bih1 = (const float*)d_in[7];
    const float* bhh1 = (const float*)d_in[8];
    const float* wfc  = (const float*)d_in[9];
    const float* bfc  = (const float*)d_in[10];
    char* ws = (char*)d_ws;

    // zero h ring buffers + flags + h2p
    hipMemsetAsync(ws + ZERO_OFF, 0, ZERO_LEN, stream);

    // prologue: pack weights into MFMA fragment order (bf16), combine biases
    pack_w<<<256,  256, 0, stream>>>(wih0, (__bf16*)(ws + OFF_PW_IH0), 0);
    pack_w<<<4096, 256, 0, stream>>>(whh0, (__bf16*)(ws + OFF_PW_HH0), 4);
    pack_w<<<4096, 256, 0, stream>>>(wih1, (__bf16*)(ws + OFF_PW_IH1), 4);
    pack_w<<<4096, 256, 0, stream>>>(whh1, (__bf16*)(ws + OFF_PW_HH1), 4);
    bias_comb<<<8, 256, 0, stream>>>(bih0, bhh0, bih1, bhh1,
                                     (float*)(ws + OFF_B0), (float*)(ws + OFF_B1));

    // one persistent kernel: weights register-resident, 201 pipelined steps
    lstm_persist<<<256, 256, 0, stream>>>(x, wfc, bfc, ws, (float*)d_out);
}

// Round 2
// 1563.407 us; speedup vs baseline: 1.2629x; 1.2256x over previous
//
#include <hip/hip_runtime.h>
#include <hip/hip_bf16.h>

#define TSEQ  200
#define BATCH 256
#define INDIM 32
#define HID   512
#define GATES 2048

typedef __bf16 bf16x8 __attribute__((ext_vector_type(8)));
typedef float  f32x4  __attribute__((ext_vector_type(4)));
typedef unsigned long long u64;

// ---- workspace layout (bytes) ----
static constexpr size_t OFF_PW_IH0 = 0;          // 2048*32*2  = 128 KB
static constexpr size_t OFF_PW_HH0 = 0x20000;    // 2048*512*2 = 2 MB
static constexpr size_t OFF_PW_IH1 = 0x220000;   // 2 MB
static constexpr size_t OFF_PW_HH1 = 0x420000;   // 2 MB
static constexpr size_t OFF_B0     = 0x620000;   // 8 KB
static constexpr size_t OFF_B1     = 0x622000;   // 8 KB
static constexpr size_t OFF_H1     = 0x624000;   // h1 ring: 4 slots x 256 KB (layer0 may run 2 ahead)
static constexpr size_t OFF_H2     = 0x724000;   // h2 ping-pong: 2 slots x 256 KB
static constexpr size_t OFF_CTR    = 0x7A4000;   // per-group flag lines (32 dwords)
static constexpr size_t OFF_H2P    = 0x7A6000;   // 512 KB fp32 (final h2)
static constexpr size_t ZERO_OFF   = OFF_H1;
static constexpr size_t ZERO_LEN   = OFF_H2P + 0x80000 - OFF_H1;

__device__ __forceinline__ float sigm(float v) { return 1.f / (1.f + __expf(-v)); }

__device__ __forceinline__ bf16x8 as_bf16x8(f32x4 v) {
    union { f32x4 f; bf16x8 b; } u; u.f = v; return u.b;
}

// Coherent 16-byte fragment load: PLAIN vector load with sc0+sc1 policy bits
// (bypasses the stale per-XCD L2, reads from MALL) -- unlike atomic loads,
// plain loads COALESCE at the TA/TCC into line requests (64 lanes x 16B
// contiguous = 1 KiB -> ~8 line transactions instead of 128 lane-atomics).
// NOTE: no compiler waitcnt tracking -- caller MUST fence with
// s_waitcnt vmcnt(0) + sched_barrier(0) before consuming results.
__device__ __forceinline__ bf16x8 load16_coh(const bf16x8* p) {
    bf16x8 v;
    asm volatile("global_load_dwordx4 %0, %1, off sc0 sc1"
                 : "=v"(v) : "v"(p) : "memory");
    return v;
}

// Coherent 16-byte store (write-through to MALL, no stale L2 allocation).
__device__ __forceinline__ void store16_coh(void* p, u64 v0, u64 v1) {
    union { u64 u[2]; f32x4 f; } cv; cv.u[0] = v0; cv.u[1] = v1;
    asm volatile("global_store_dwordx4 %0, %1, off sc0 sc1"
                 :: "v"(p), "v"(cv.f) : "memory");
}

// Coherent flag load with self-contained waitcnt (1 coalesced line request
// per poll across the 32 polling lanes, vs 32 atomic transactions before).
__device__ __forceinline__ unsigned load_flag_coh(const unsigned* p) {
    unsigned v;
    asm volatile("global_load_dword %0, %1, off sc0 sc1\n\t"
                 "s_waitcnt vmcnt(0)"
                 : "=v"(v) : "v"(p) : "memory");
    return v;
}

// Pack weight matrix W[2048][K] (fp32, row-major) into MFMA B-fragment order (bf16).
__global__ void pack_w(const float* __restrict__ W, __bf16* __restrict__ out, int ktlog2)
{
    int tid = blockIdx.x * 256 + threadIdx.x;
    int K = 32 << ktlog2;
    int j    = tid & 7;
    int lane = (tid >> 3) & 63;
    int rest = tid >> 9;
    int kt   = rest & ((1 << ktlog2) - 1);
    int r2   = rest >> ktlog2;
    int lnt  = r2 & 7;
    int bn   = r2 >> 3;
    int type = lnt >> 1, half = lnt & 1;
    int g    = type * 512 + bn * 32 + half * 16 + (lane & 15);
    int kcol = kt * 32 + (lane >> 4) * 8 + j;
    out[tid] = (__bf16)W[g * K + kcol];
}

__global__ void bias_comb(const float* __restrict__ a0, const float* __restrict__ a1,
                          const float* __restrict__ a2, const float* __restrict__ a3,
                          float* __restrict__ o0, float* __restrict__ o1)
{
    int tid = blockIdx.x * 256 + threadIdx.x;
    if (tid < GATES) { o0[tid] = a0[tid] + a1[tid]; o1[tid] = a2[tid] + a3[tid]; }
}

// Persistent pipelined 2-layer LSTM, weights register-resident.
// Grid: 256 blocks x 256 threads (4 waves). Blocks 0..127 layer0, 128..255 layer1.
// This revision: ALL inter-block data movement (h fragments, h stores, flag
// polls) converted from agent-scope atomics (per-lane MALL transactions,
// transaction-rate-bound) to plain sc0/sc1-flagged vector ops (coalesced).
__global__ __launch_bounds__(256, 1) void lstm_persist(const float* __restrict__ x,
                                                       const float* __restrict__ wfc,
                                                       const float* __restrict__ bfc,
                                                       char* __restrict__ ws,
                                                       float* __restrict__ out)
{
    const int layer = blockIdx.x >> 7;
    const int lb    = blockIdx.x & 127;
    const int mtp   = lb >> 4;            // batch group: [mtp*32, +32)
    const int bn    = lb & 15;            // hidden tile: [bn*32, +32)
    const int wid   = threadIdx.x >> 6;
    const int half  = wid & 1;
    const int kh    = wid >> 1;
    const int lane  = threadIdx.x & 63;
    const int q     = lane >> 4;
    const int c16   = lane & 15;
    unsigned* flg   = (unsigned*)(ws + OFF_CTR) + (size_t)mtp * 64;  // 32 flags, 1 line

    __shared__ float  red[2][64][33];     // padded: conflict-free cross-wave reduction
    __shared__ __bf16 htr[1024];          // h transpose staging (kh0 waves only)

    const float* bias = (const float*)(ws + (layer ? OFF_B1 : OFF_B0));
    const int hidx = bn * 32 + half * 16 + c16;     // C/D col = lane&15
    const float bi  = bias[hidx];
    const float bff = bias[512 + hidx];
    const float bg  = bias[1024 + hidx];
    const float bo  = bias[1536 + hidx];

    const bf16x8* __restrict__ pBx = (const bf16x8*)(ws + OFF_PW_IH0);
    const bf16x8* __restrict__ pBh = (const bf16x8*)(ws + OFF_PW_HH0);
    const bf16x8* __restrict__ pB1 = (const bf16x8*)(ws + OFF_PW_IH1);
    const bf16x8* __restrict__ pB2 = (const bf16x8*)(ws + OFF_PW_HH1);
    float* __restrict__ h2p = (float*)(ws + OFF_H2P);

    // ---- preload weight slice into registers (once; written by prior dispatch) ----
    f32x4 Bw[64];                         // layer1: [kt(16)][ty(4)]; layer0: [kt(8)][ty(4)]
    f32x4 Bx[4];                          // layer0 x-projection frags
    if (layer == 0) {
        #pragma unroll
        for (int j = 0; j < 8; ++j)
            #pragma unroll
            for (int ty = 0; ty < 4; ++ty)
                Bw[j * 4 + ty] = *(const f32x4*)&pBh[((bn * 8 + ty * 2 + half) * 16 + kh * 8 + j) * 64 + lane];
        #pragma unroll
        for (int ty = 0; ty < 4; ++ty)
            Bx[ty] = *(const f32x4*)&pBx[(bn * 8 + ty * 2 + half) * 64 + lane];
    } else {
        const bf16x8* __restrict__ pW = kh ? pB2 : pB1;
        #pragma unroll
        for (int j = 0; j < 16; ++j)
            #pragma unroll
            for (int ty = 0; ty < 4; ++ty)
                Bw[j * 4 + ty] = *(const f32x4*)&pW[((bn * 8 + ty * 2 + half) * 16 + j) * 64 + lane];
    }

    float creg[8] = {0.f,0.f,0.f,0.f,0.f,0.f,0.f,0.f};   // c state (kh0 waves)

    // 16 A-frag loads (2 m-tiles x 8 kt); coalesced coherent loads, in-order
    auto loadA = [&](bf16x8* dst, const bf16x8* pA, int kt0) {
        #pragma unroll
        for (int j = 0; j < 8; ++j) {
            dst[j]     = load16_coh(&pA[((mtp * 2 + 0) * 16 + kt0 + j) * 64 + lane]);
            dst[8 + j] = load16_coh(&pA[((mtp * 2 + 1) * 16 + kt0 + j) * 64 + lane]);
        }
    };

    for (int k = 0; k <= TSEQ; ++k) {
        const bool active = layer ? (k >= 1) : (k < TSEQ);
        if (active) {
            const int t = k - layer;
            f32x4 acc[2][4] = {};

            // h1 ring: layer0 writes slot k&3 (t=k); both layers read t=k-1 at slot (k+3)&3
            const size_t h1rd = OFF_H1 + (size_t)((k + 3) & 3) * 0x40000;

            if (layer == 0) {
                const bf16x8* __restrict__ pA = (const bf16x8*)(ws + h1rd);
                bf16x8 af[16];
                loadA(af, pA, kh * 8);
                bf16x8 ax[2];
                if (kh == 0) {
                    // x projection inputs (plain cached loads; x is read-only)
                    #pragma unroll
                    for (int m = 0; m < 2; ++m) {
                        const int b = (mtp * 2 + m) * 16 + c16;
                        const float* xp = x + ((size_t)b * TSEQ + t) * INDIM + q * 8;
                        float4 xlo = *(const float4*)xp;
                        float4 xhi = *(const float4*)(xp + 4);
                        ax[m][0] = (__bf16)xlo.x; ax[m][1] = (__bf16)xlo.y;
                        ax[m][2] = (__bf16)xlo.z; ax[m][3] = (__bf16)xlo.w;
                        ax[m][4] = (__bf16)xhi.x; ax[m][5] = (__bf16)xhi.y;
                        ax[m][6] = (__bf16)xhi.z; ax[m][7] = (__bf16)xhi.w;
                    }
                }
                // fence: asm loads complete before any MFMA consumes them
                asm volatile("s_waitcnt vmcnt(0)" ::: "memory");
                __builtin_amdgcn_sched_barrier(0);
                if (kh == 0) {
                    #pragma unroll
                    for (int m = 0; m < 2; ++m)
                        #pragma unroll
                        for (int ty = 0; ty < 4; ++ty)
                            acc[m][ty] = __builtin_amdgcn_mfma_f32_16x16x32_bf16(ax[m], as_bf16x8(Bx[ty]), acc[m][ty], 0, 0, 0);
                }
                #pragma unroll
                for (int j = 0; j < 8; ++j) {
                    #pragma unroll
                    for (int ty = 0; ty < 4; ++ty) {
                        acc[0][ty] = __builtin_amdgcn_mfma_f32_16x16x32_bf16(af[j],     as_bf16x8(Bw[j * 4 + ty]), acc[0][ty], 0, 0, 0);
                        acc[1][ty] = __builtin_amdgcn_mfma_f32_16x16x32_bf16(af[8 + j], as_bf16x8(Bw[j * 4 + ty]), acc[1][ty], 0, 0, 0);
                    }
                }
            } else {
                const bf16x8* __restrict__ pA = kh
                    ? (const bf16x8*)(ws + OFF_H2 + (size_t)((k + 1) & 1) * 0x40000)
                    : (const bf16x8*)(ws + h1rd);
                bf16x8 a0[16], a1[16];
                loadA(a0, pA, 0);
                loadA(a1, pA, 8);
                // fence: asm loads complete before any MFMA consumes them
                asm volatile("s_waitcnt vmcnt(0)" ::: "memory");
                __builtin_amdgcn_sched_barrier(0);
                #pragma unroll
                for (int j = 0; j < 8; ++j) {
                    #pragma unroll
                    for (int ty = 0; ty < 4; ++ty) {
                        acc[0][ty] = __builtin_amdgcn_mfma_f32_16x16x32_bf16(a0[j],     as_bf16x8(Bw[j * 4 + ty]), acc[0][ty], 0, 0, 0);
                        acc[1][ty] = __builtin_amdgcn_mfma_f32_16x16x32_bf16(a0[8 + j], as_bf16x8(Bw[j * 4 + ty]), acc[1][ty], 0, 0, 0);
                    }
                }
                #pragma unroll
                for (int j = 0; j < 8; ++j) {
                    #pragma unroll
                    for (int ty = 0; ty < 4; ++ty) {
                        acc[0][ty] = __builtin_amdgcn_mfma_f32_16x16x32_bf16(a1[j],     as_bf16x8(Bw[(8 + j) * 4 + ty]), acc[0][ty], 0, 0, 0);
                        acc[1][ty] = __builtin_amdgcn_mfma_f32_16x16x32_bf16(a1[8 + j], as_bf16x8(Bw[(8 + j) * 4 + ty]), acc[1][ty], 0, 0, 0);
                    }
                }
            }

            // ---- cross-wave K reduction ----
            if (kh == 1) {
                #pragma unroll
                for (int m = 0; m < 2; ++m)
                    #pragma unroll
                    for (int ty = 0; ty < 4; ++ty)
                        #pragma unroll
                        for (int r = 0; r < 4; ++r)
                            red[half][lane][m * 16 + ty * 4 + r] = acc[m][ty][r];
            }
            __syncthreads();

            if (kh == 0) {
                __bf16* __restrict__ hout = (__bf16*)(ws + (layer
                    ? OFF_H2 + (size_t)(k & 1) * 0x40000
                    : OFF_H1 + (size_t)(k & 3) * 0x40000));
                #pragma unroll
                for (int m = 0; m < 2; ++m) {
                    #pragma unroll
                    for (int r = 0; r < 4; ++r) {
                        float pi = acc[m][0][r] + red[half][lane][m * 16 + r]      + bi;
                        float pf = acc[m][1][r] + red[half][lane][m * 16 + 4 + r]  + bff;
                        float pg = acc[m][2][r] + red[half][lane][m * 16 + 8 + r]  + bg;
                        float po = acc[m][3][r] + red[half][lane][m * 16 + 12 + r] + bo;
                        float cn = sigm(pf) * creg[m * 4 + r] + sigm(pi) * tanhf(pg);
                        float hn = sigm(po) * tanhf(cn);
                        creg[m * 4 + r] = cn;
                        htr[half * 512 + (m * 16 + q * 4 + r) * 16 + c16] = (__bf16)hn;
                        if (layer == 1 && k == TSEQ) {
                            const int b = (mtp * 2 + m) * 16 + q * 4 + r;
                            __hip_atomic_store(&h2p[b * HID + hidx], hn,
                                               __ATOMIC_RELAXED, __HIP_MEMORY_SCOPE_AGENT);
                        }
                    }
                }
                // wave-local LDS transpose -> one coalesced 16B coherent store
                const int bt   = lane >> 5;
                const int qa1  = (lane >> 4) & 1;
                const int b15r = lane & 15;
                const u64* lp = (const u64*)&htr[half * 512 + (bt * 16 + b15r) * 16 + qa1 * 8];
                u64 v0 = lp[0], v1 = lp[1];
                const int f = (((mtp * 2 + bt) * 16) + bn) * 64 + (half * 2 + qa1) * 16 + b15r;
                u64* gp = (u64*)hout + (size_t)f * 2;
                store16_coh(gp, v0, v1);
            }
        }

        // ---- flag barrier: plain per-block stores + one coalesced 32-lane poll ----
        asm volatile("s_waitcnt vmcnt(0)" ::: "memory");
        __syncthreads();
        if (threadIdx.x == 0)
            __hip_atomic_store(flg + layer * 16 + bn, (unsigned)(k + 1),
                               __ATOMIC_RELAXED, __HIP_MEMORY_SCOPE_AGENT);
        if (threadIdx.x < 32) {
            const int need = (layer == 0 && threadIdx.x >= 16 && k < TSEQ) ? (k - 1) : (k + 1);
            while ((int)load_flag_coh(flg + threadIdx.x) < need)
                __builtin_amdgcn_s_sleep(1);
        }
        __syncthreads();
    }

    // ---- fused FC epilogue: one batch per block (group-local mapping) ----
    if (threadIdx.x < 64) {
        const int b = mtp * 32 + layer * 16 + bn;
        const float* h = h2p + b * HID;
        float hv[8];
        #pragma unroll
        for (int j = 0; j < 8; ++j)
            hv[j] = __hip_atomic_load(&h[lane * 8 + j], __ATOMIC_RELAXED, __HIP_MEMORY_SCOPE_AGENT);
        float y[7];
        #pragma unroll
        for (int o = 0; o < 7; ++o) {
            const float* wrow = wfc + o * HID;
            float s = 0.f;
            #pragma unroll
            for (int j = 0; j < 8; ++j) s += hv[j] * wrow[lane * 8 + j];
            #pragma unroll
            for (int off = 32; off >= 1; off >>= 1) s += __shfl_down(s, off);
            y[o] = s;
        }
        if (lane == 0) {
            out[b * 3 + 0] = sigm(y[0] + bfc[0]);
            out[b * 3 + 1] = sigm(y[1] + bfc[1]);
            out[b * 3 + 2] = sigm(y[2] + bfc[2]);
            float r0 = tanhf(y[3] + bfc[3]);
            float r1 = tanhf(y[4] + bfc[4]);
            float r2 = tanhf(y[5] + bfc[5]);
            float r3 = tanhf(y[6] + bfc[6]);
            float n = sqrtf(r0 * r0 + r1 * r1 + r2 * r2 + r3 * r3);
            n = fmaxf(n, 1e-12f);
            out[768 + b * 4 + 0] = r0 / n;
            out[768 + b * 4 + 1] = r1 / n;
            out[768 + b * 4 + 2] = r2 / n;
            out[768 + b * 4 + 3] = r3 / n;
        }
    }
}

extern "C" void kernel_launch(void* const* d_in, const int* in_sizes, int n_in,
                              void* d_out, int out_size, void* d_ws, size_t ws_size,
                              hipStream_t stream)
{
    const float* x    = (const float*)d_in[0];
    const float* wih0 = (const float*)d_in[1];
    const float* whh0 = (const float*)d_in[2];
    const float* bih0 = (const float*)d_in[3];
    const float* bhh0 = (const float*)d_in[4];
    const float* wih1 = (const float*)d_in[5];
    const float* whh1 = (const float*)d_in[6];
    const float* bih1 = (const float*)d_in[7];
    const float* bhh1 = (const float*)d_in[8];
    const float* wfc  = (const float*)d_in[9];
    const float* bfc  = (const float*)d_in[10];
    char* ws = (char*)d_ws;

    // zero h ring buffers + flags + h2p
    hipMemsetAsync(ws + ZERO_OFF, 0, ZERO_LEN, stream);

    // prologue: pack weights into MFMA fragment order (bf16), combine biases
    pack_w<<<256,  256, 0, stream>>>(wih0, (__bf16*)(ws + OFF_PW_IH0), 0);
    pack_w<<<4096, 256, 0, stream>>>(whh0, (__bf16*)(ws + OFF_PW_HH0), 4);
    pack_w<<<4096, 256, 0, stream>>>(wih1, (__bf16*)(ws + OFF_PW_IH1), 4);
    pack_w<<<4096, 256, 0, stream>>>(whh1, (__bf16*)(ws + OFF_PW_HH1), 4);
    bias_comb<<<8, 256, 0, stream>>>(bih0, bhh0, bih1, bhh1,
                                     (float*)(ws + OFF_B0), (float*)(ws + OFF_B1));

    // one persistent kernel: weights register-resident, 201 pipelined steps
    lstm_persist<<<256, 256, 0, stream>>>(x, wfc, bfc, ws, (float*)d_out);
}

// Round 5
// 1432.814 us; speedup vs baseline: 1.3780x; 1.0911x over previous
//
#include <hip/hip_runtime.h>
#include <hip/hip_bf16.h>

#define TSEQ  200
#define BATCH 256
#define INDIM 32
#define HID   512
#define GATES 2048

typedef __bf16 bf16x8 __attribute__((ext_vector_type(8)));
typedef float  f32x4  __attribute__((ext_vector_type(4)));
typedef unsigned long long u64;

// ---- workspace layout (bytes) ----
static constexpr size_t OFF_PW_IH0 = 0;          // 2048*32*2  = 128 KB
static constexpr size_t OFF_PW_HH0 = 0x20000;    // 2048*512*2 = 2 MB
static constexpr size_t OFF_PW_IH1 = 0x220000;   // 2 MB
static constexpr size_t OFF_PW_HH1 = 0x420000;   // 2 MB
static constexpr size_t OFF_B0     = 0x620000;   // 8 KB
static constexpr size_t OFF_B1     = 0x622000;   // 8 KB
static constexpr size_t OFF_H1     = 0x624000;   // h1 ring: 4 slots x 256 KB
static constexpr size_t OFF_H2     = 0x724000;   // h2 ping-pong: 2 slots x 256 KB
static constexpr size_t OFF_CTR    = 0x7A4000;   // per-group flag lines
static constexpr size_t OFF_H2P    = 0x7A6000;   // 512 KB fp32 (final h2)
static constexpr size_t ZERO_OFF   = OFF_H1;
static constexpr size_t ZERO_LEN   = OFF_H2P + 0x80000 - OFF_H1;

__device__ __forceinline__ float sigm(float v) { return 1.f / (1.f + __expf(-v)); }

// guarded fast tanh: e = exp(-2|v|) in (0,1]; tanh(|v|) = (1-e)/(1+e); restore sign.
__device__ __forceinline__ float tanh_fast(float v) {
    float e = __expf(-2.0f * fabsf(v));
    float t = (1.0f - e) / (1.0f + e);
    return copysignf(t, v);
}

__device__ __forceinline__ bf16x8 as_bf16x8(f32x4 v) {
    union { f32x4 f; bf16x8 b; } u; u.f = v; return u.b;
}

// Coherent 16-byte fragment load: PLAIN vector load with sc0+sc1 policy bits
// (bypasses the stale per-XCD L2, reads from MALL); coalesces at the TA/TCC.
// NOTE: not waitcnt-tracked by the compiler -- callers MUST fence with
// s_waitcnt vmcnt(0) + sched_barrier(0) before consuming results (rule 18).
__device__ __forceinline__ bf16x8 load16_coh(const bf16x8* p) {
    bf16x8 v;
    asm volatile("global_load_dwordx4 %0, %1, off sc0 sc1"
                 : "=v"(v) : "v"(p) : "memory");
    return v;
}

// Coherent 16-byte store (write-through to MALL, no stale L2 allocation).
__device__ __forceinline__ void store16_coh(void* p, u64 v0, u64 v1) {
    union { u64 u[2]; f32x4 f; } cv; cv.u[0] = v0; cv.u[1] = v1;
    asm volatile("global_store_dwordx4 %0, %1, off sc0 sc1"
                 :: "v"(p), "v"(cv.f) : "memory");
}

// Coherent flag load with self-contained waitcnt.
__device__ __forceinline__ unsigned load_flag_coh(const unsigned* p) {
    unsigned v;
    asm volatile("global_load_dword %0, %1, off sc0 sc1\n\t"
                 "s_waitcnt vmcnt(0)"
                 : "=v"(v) : "v"(p) : "memory");
    return v;
}

// Pack weight matrix W[2048][K] (fp32, row-major) into MFMA B-fragment order (bf16).
__global__ void pack_w(const float* __restrict__ W, __bf16* __restrict__ out, int ktlog2)
{
    int tid = blockIdx.x * 256 + threadIdx.x;
    int K = 32 << ktlog2;
    int j    = tid & 7;
    int lane = (tid >> 3) & 63;
    int rest = tid >> 9;
    int kt   = rest & ((1 << ktlog2) - 1);
    int r2   = rest >> ktlog2;
    int lnt  = r2 & 7;
    int bn   = r2 >> 3;
    int type = lnt >> 1, half = lnt & 1;
    int g    = type * 512 + bn * 32 + half * 16 + (lane & 15);
    int kcol = kt * 32 + (lane >> 4) * 8 + j;
    out[tid] = (__bf16)W[g * K + kcol];
}

__global__ void bias_comb(const float* __restrict__ a0, const float* __restrict__ a1,
                          const float* __restrict__ a2, const float* __restrict__ a3,
                          float* __restrict__ o0, float* __restrict__ o1)
{
    int tid = blockIdx.x * 256 + threadIdx.x;
    if (tid < GATES) { o0[tid] = a0[tid] + a1[tid]; o1[tid] = a2[tid] + a3[tid]; }
}

// Persistent pipelined 2-layer LSTM, weights register-resident.
// Grid: 256 blocks x 256 threads (4 waves). Blocks 0..127 layer0, 128..255 layer1.
// vs round 2 (verified 1563 us): A-fragment loads DEDUPLICATED via LDS staging.
// The (kh, half=0) and (kh, half=1) waves used to issue bitwise-identical
// coherent loads (frag index is half-independent); now each wave loads only
// its half's m-tile, stages to LDS, and all waves read from LDS. Coherent
// (MALL) read traffic per step: 24 MB -> 12 MB. Sync topology unchanged.
__global__ __launch_bounds__(256, 1) void lstm_persist(const float* __restrict__ x,
                                                       const float* __restrict__ wfc,
                                                       const float* __restrict__ bfc,
                                                       char* __restrict__ ws,
                                                       float* __restrict__ out)
{
    const int layer = blockIdx.x >> 7;
    const int lb    = blockIdx.x & 127;
    const int mtp   = lb >> 4;            // batch group: [mtp*32, +32)
    const int bn    = lb & 15;            // hidden tile: [bn*32, +32)
    const int wid   = threadIdx.x >> 6;
    const int half  = wid & 1;
    const int kh    = wid >> 1;
    const int lane  = threadIdx.x & 63;
    const int q     = lane >> 4;
    const int c16   = lane & 15;
    unsigned* flg   = (unsigned*)(ws + OFF_CTR) + (size_t)mtp * 64;  // 32 flags, 1 line

    __shared__ float  red[2][64][33];     // padded: conflict-free cross-wave reduction
    __shared__ __bf16 htr[1024];          // h transpose staging (kh0 waves only)
    __shared__ bf16x8 stg[2][2][16][64];  // A-frag dedup staging [kh][m][kt][lane], 64 KB

    const float* bias = (const float*)(ws + (layer ? OFF_B1 : OFF_B0));
    const int hidx = bn * 32 + half * 16 + c16;     // C/D col = lane&15
    const float bi  = bias[hidx];
    const float bff = bias[512 + hidx];
    const float bg  = bias[1024 + hidx];
    const float bo  = bias[1536 + hidx];

    const bf16x8* __restrict__ pBx = (const bf16x8*)(ws + OFF_PW_IH0);
    const bf16x8* __restrict__ pBh = (const bf16x8*)(ws + OFF_PW_HH0);
    const bf16x8* __restrict__ pB1 = (const bf16x8*)(ws + OFF_PW_IH1);
    const bf16x8* __restrict__ pB2 = (const bf16x8*)(ws + OFF_PW_HH1);
    float* __restrict__ h2p = (float*)(ws + OFF_H2P);

    // ---- preload weight slice into registers (once; written by prior dispatch) ----
    f32x4 Bw[64];                         // layer1: [kt(16)][ty(4)]; layer0: [kt(8)][ty(4)]
    f32x4 Bx[4];                          // layer0 x-projection frags
    if (layer == 0) {
        #pragma unroll
        for (int j = 0; j < 8; ++j)
            #pragma unroll
            for (int ty = 0; ty < 4; ++ty)
                Bw[j * 4 + ty] = *(const f32x4*)&pBh[((bn * 8 + ty * 2 + half) * 16 + kh * 8 + j) * 64 + lane];
        #pragma unroll
        for (int ty = 0; ty < 4; ++ty)
            Bx[ty] = *(const f32x4*)&pBx[(bn * 8 + ty * 2 + half) * 64 + lane];
    } else {
        const bf16x8* __restrict__ pW = kh ? pB2 : pB1;
        #pragma unroll
        for (int j = 0; j < 16; ++j)
            #pragma unroll
            for (int ty = 0; ty < 4; ++ty)
                Bw[j * 4 + ty] = *(const f32x4*)&pW[((bn * 8 + ty * 2 + half) * 16 + j) * 64 + lane];
    }

    float creg[8] = {0.f,0.f,0.f,0.f,0.f,0.f,0.f,0.f};   // c state (kh0 waves)

    for (int k = 0; k <= TSEQ; ++k) {
        const bool active = layer ? (k >= 1) : (k < TSEQ);
        if (active) {
            const int t = k - layer;
            f32x4 acc[2][4] = {};

            // h1 ring: layer0 writes slot k&3 (t=k); both layers read t=k-1 at slot (k+3)&3
            const size_t h1rd = OFF_H1 + (size_t)((k + 3) & 3) * 0x40000;

            if (layer == 0) {
                const bf16x8* __restrict__ pA = (const bf16x8*)(ws + h1rd);
                // dedup: this wave loads only m-tile == half, kt range == kh*8..+8
                bf16x8 tmp0[8];
                #pragma unroll
                for (int j = 0; j < 8; ++j)
                    tmp0[j] = load16_coh(&pA[((mtp * 2 + half) * 16 + kh * 8 + j) * 64 + lane]);
                bf16x8 ax[2];
                if (kh == 0) {
                    // x projection inputs (plain cached loads; x is read-only)
                    #pragma unroll
                    for (int m = 0; m < 2; ++m) {
                        const int b = (mtp * 2 + m) * 16 + c16;
                        const float* xp = x + ((size_t)b * TSEQ + t) * INDIM + q * 8;
                        float4 xlo = *(const float4*)xp;
                        float4 xhi = *(const float4*)(xp + 4);
                        ax[m][0] = (__bf16)xlo.x; ax[m][1] = (__bf16)xlo.y;
                        ax[m][2] = (__bf16)xlo.z; ax[m][3] = (__bf16)xlo.w;
                        ax[m][4] = (__bf16)xhi.x; ax[m][5] = (__bf16)xhi.y;
                        ax[m][6] = (__bf16)xhi.z; ax[m][7] = (__bf16)xhi.w;
                    }
                }
                // fence: asm loads complete before staging/consuming (rule 18)
                asm volatile("s_waitcnt vmcnt(0)" ::: "memory");
                __builtin_amdgcn_sched_barrier(0);
                #pragma unroll
                for (int j = 0; j < 8; ++j)
                    stg[kh][half][j][lane] = tmp0[j];
                __syncthreads();
                bf16x8 af[16];
                #pragma unroll
                for (int j = 0; j < 8; ++j) {
                    af[j]     = stg[kh][0][j][lane];
                    af[8 + j] = stg[kh][1][j][lane];
                }
                if (kh == 0) {
                    #pragma unroll
                    for (int m = 0; m < 2; ++m)
                        #pragma unroll
                        for (int ty = 0; ty < 4; ++ty)
                            acc[m][ty] = __builtin_amdgcn_mfma_f32_16x16x32_bf16(ax[m], as_bf16x8(Bx[ty]), acc[m][ty], 0, 0, 0);
                }
                #pragma unroll
                for (int j = 0; j < 8; ++j) {
                    #pragma unroll
                    for (int ty = 0; ty < 4; ++ty) {
                        acc[0][ty] = __builtin_amdgcn_mfma_f32_16x16x32_bf16(af[j],     as_bf16x8(Bw[j * 4 + ty]), acc[0][ty], 0, 0, 0);
                        acc[1][ty] = __builtin_amdgcn_mfma_f32_16x16x32_bf16(af[8 + j], as_bf16x8(Bw[j * 4 + ty]), acc[1][ty], 0, 0, 0);
                    }
                }
            } else {
                const bf16x8* __restrict__ pA = kh
                    ? (const bf16x8*)(ws + OFF_H2 + (size_t)((k + 1) & 1) * 0x40000)
                    : (const bf16x8*)(ws + h1rd);
                // dedup: this wave loads only m-tile == half, all 16 kt
                bf16x8 tmp[16];
                #pragma unroll
                for (int j = 0; j < 16; ++j)
                    tmp[j] = load16_coh(&pA[((mtp * 2 + half) * 16 + j) * 64 + lane]);
                asm volatile("s_waitcnt vmcnt(0)" ::: "memory");
                __builtin_amdgcn_sched_barrier(0);
                #pragma unroll
                for (int j = 0; j < 16; ++j)
                    stg[kh][half][j][lane] = tmp[j];
                __syncthreads();
                bf16x8 a0[16], a1[16];
                #pragma unroll
                for (int j = 0; j < 8; ++j) {
                    a0[j]     = stg[kh][0][j][lane];
                    a0[8 + j] = stg[kh][1][j][lane];
                    a1[j]     = stg[kh][0][8 + j][lane];
                    a1[8 + j] = stg[kh][1][8 + j][lane];
                }
                #pragma unroll
                for (int j = 0; j < 8; ++j) {
                    #pragma unroll
                    for (int ty = 0; ty < 4; ++ty) {
                        acc[0][ty] = __builtin_amdgcn_mfma_f32_16x16x32_bf16(a0[j],     as_bf16x8(Bw[j * 4 + ty]), acc[0][ty], 0, 0, 0);
                        acc[1][ty] = __builtin_amdgcn_mfma_f32_16x16x32_bf16(a0[8 + j], as_bf16x8(Bw[j * 4 + ty]), acc[1][ty], 0, 0, 0);
                    }
                }
                #pragma unroll
                for (int j = 0; j < 8; ++j) {
                    #pragma unroll
                    for (int ty = 0; ty < 4; ++ty) {
                        acc[0][ty] = __builtin_amdgcn_mfma_f32_16x16x32_bf16(a1[j],     as_bf16x8(Bw[(8 + j) * 4 + ty]), acc[0][ty], 0, 0, 0);
                        acc[1][ty] = __builtin_amdgcn_mfma_f32_16x16x32_bf16(a1[8 + j], as_bf16x8(Bw[(8 + j) * 4 + ty]), acc[1][ty], 0, 0, 0);
                    }
                }
            }

            // ---- cross-wave K reduction ----
            if (kh == 1) {
                #pragma unroll
                for (int m = 0; m < 2; ++m)
                    #pragma unroll
                    for (int ty = 0; ty < 4; ++ty)
                        #pragma unroll
                        for (int r = 0; r < 4; ++r)
                            red[half][lane][m * 16 + ty * 4 + r] = acc[m][ty][r];
            }
            __syncthreads();

            if (kh == 0) {
                __bf16* __restrict__ hout = (__bf16*)(ws + (layer
                    ? OFF_H2 + (size_t)(k & 1) * 0x40000
                    : OFF_H1 + (size_t)(k & 3) * 0x40000));
                #pragma unroll
                for (int m = 0; m < 2; ++m) {
                    #pragma unroll
                    for (int r = 0; r < 4; ++r) {
                        float pi = acc[m][0][r] + red[half][lane][m * 16 + r]      + bi;
                        float pf = acc[m][1][r] + red[half][lane][m * 16 + 4 + r]  + bff;
                        float pg = acc[m][2][r] + red[half][lane][m * 16 + 8 + r]  + bg;
                        float po = acc[m][3][r] + red[half][lane][m * 16 + 12 + r] + bo;
                        float cn = sigm(pf) * creg[m * 4 + r] + sigm(pi) * tanh_fast(pg);
                        float hn = sigm(po) * tanh_fast(cn);
                        creg[m * 4 + r] = cn;
                        htr[half * 512 + (m * 16 + q * 4 + r) * 16 + c16] = (__bf16)hn;
                        if (layer == 1 && k == TSEQ) {
                            const int b = (mtp * 2 + m) * 16 + q * 4 + r;
                            __hip_atomic_store(&h2p[b * HID + hidx], hn,
                                               __ATOMIC_RELAXED, __HIP_MEMORY_SCOPE_AGENT);
                        }
                    }
                }
                // wave-local LDS transpose -> one coalesced 16B coherent store
                const int bt   = lane >> 5;
                const int qa1  = (lane >> 4) & 1;
                const int b15r = lane & 15;
                const u64* lp = (const u64*)&htr[half * 512 + (bt * 16 + b15r) * 16 + qa1 * 8];
                u64 v0 = lp[0], v1 = lp[1];
                const int f = (((mtp * 2 + bt) * 16) + bn) * 64 + (half * 2 + qa1) * 16 + b15r;
                u64* gp = (u64*)hout + (size_t)f * 2;
                store16_coh(gp, v0, v1);
            }
        }

        // ---- flag barrier: per-block stores + one coalesced 32-lane poll ----
        asm volatile("s_waitcnt vmcnt(0)" ::: "memory");
        __syncthreads();
        if (threadIdx.x == 0)
            __hip_atomic_store(flg + layer * 16 + bn, (unsigned)(k + 1),
                               __ATOMIC_RELAXED, __HIP_MEMORY_SCOPE_AGENT);
        if (threadIdx.x < 32) {
            const int need = (layer == 0 && threadIdx.x >= 16 && k < TSEQ) ? (k - 1) : (k + 1);
            while ((int)load_flag_coh(flg + threadIdx.x) < need)
                __builtin_amdgcn_s_sleep(1);
        }
        __syncthreads();
    }

    // ---- fused FC epilogue: one batch per block (group-local mapping) ----
    if (threadIdx.x < 64) {
        const int b = mtp * 32 + layer * 16 + bn;
        const float* h = h2p + b * HID;
        float hv[8];
        #pragma unroll
        for (int j = 0; j < 8; ++j)
            hv[j] = __hip_atomic_load(&h[lane * 8 + j], __ATOMIC_RELAXED, __HIP_MEMORY_SCOPE_AGENT);
        float y[7];
        #pragma unroll
        for (int o = 0; o < 7; ++o) {
            const float* wrow = wfc + o * HID;
            float s = 0.f;
            #pragma unroll
            for (int j = 0; j < 8; ++j) s += hv[j] * wrow[lane * 8 + j];
            #pragma unroll
            for (int off = 32; off >= 1; off >>= 1) s += __shfl_down(s, off);
            y[o] = s;
        }
        if (lane == 0) {
            out[b * 3 + 0] = sigm(y[0] + bfc[0]);
            out[b * 3 + 1] = sigm(y[1] + bfc[1]);
            out[b * 3 + 2] = sigm(y[2] + bfc[2]);
            float r0 = tanh_fast(y[3] + bfc[3]);
            float r1 = tanh_fast(y[4] + bfc[4]);
            float r2 = tanh_fast(y[5] + bfc[5]);
            float r3 = tanh_fast(y[6] + bfc[6]);
            float n = sqrtf(r0 * r0 + r1 * r1 + r2 * r2 + r3 * r3);
            n = fmaxf(n, 1e-12f);
            out[768 + b * 4 + 0] = r0 / n;
            out[768 + b * 4 + 1] = r1 / n;
            out[768 + b * 4 + 2] = r2 / n;
            out[768 + b * 4 + 3] = r3 / n;
        }
    }
}

extern "C" void kernel_launch(void* const* d_in, const int* in_sizes, int n_in,
                              void* d_out, int out_size, void* d_ws, size_t ws_size,
                              hipStream_t stream)
{
    const float* x    = (const float*)d_in[0];
    const float* wih0 = (const float*)d_in[1];
    const float* whh0 = (const float*)d_in[2];
    const float* bih0 = (const float*)d_in[3];
    const float* bhh0 = (const float*)d_in[4];
    const float* wih1 = (const float*)d_in[5];
    const float* whh1 = (const float*)d_in[6];
    const float* bih1 = (const float*)d_in[7];
    const float* bhh1 = (const float*)d_in[8];
    const float* wfc  = (const float*)d_in[9];
    const float* bfc  = (const float*)d_in[10];
    char* ws = (char*)d_ws;

    // zero h ring buffers + flags + h2p
    hipMemsetAsync(ws + ZERO_OFF, 0, ZERO_LEN, stream);

    // prologue: pack weights into MFMA fragment order (bf16), combine biases
    pack_w<<<256,  256, 0, stream>>>(wih0, (__bf16*)(ws + OFF_PW_IH0), 0);
    pack_w<<<4096, 256, 0, stream>>>(whh0, (__bf16*)(ws + OFF_PW_HH0), 4);
    pack_w<<<4096, 256, 0, stream>>>(wih1, (__bf16*)(ws + OFF_PW_IH1), 4);
    pack_w<<<4096, 256, 0, stream>>>(whh1, (__bf16*)(ws + OFF_PW_HH1), 4);
    bias_comb<<<8, 256, 0, stream>>>(bih0, bhh0, bih1, bhh1,
                                     (float*)(ws + OFF_B0), (float*)(ws + OFF_B1));

    // one persistent kernel: weights register-resident, 201 pipelined steps
    lstm_persist<<<256, 256, 0, stream>>>(x, wfc, bfc, ws, (float*)d_out);
}